// Round 1
// baseline (1502.440 us; speedup 1.0000x reference)
//
#include <hip/hip_runtime.h>

#define HIDDEN 51
#define LSEQ 1000
#define UNROLL 8    // steps buffered between butterfly/store groups
#define NB 2        // batch elements per wave (share the 208-AGPR U matrix)

typedef float v2f __attribute__((ext_vector_type(2)));

// Branch-free tanh: tanh(v) = 1 - 2/(exp2(2*log2e*v)+1). Saturates to +/-1.
__device__ __forceinline__ float fast_tanh(float v) {
    float e = __builtin_amdgcn_exp2f(v * 2.885390081777927f);  // 2*log2(e)
    float r = __builtin_amdgcn_rcpf(e + 1.0f);
    return fmaf(-2.0f, r, 1.0f);
}

// One wave per NB batch elements, no barriers.
// Evidence (R0 counters): 1 wave/SIMD (Occupancy 11.5%), VALUBusy 44%,
// HBM ~0 -> pure dependency-latency bound. The per-step serial tail
// (26-deep FMA chain end, gate sums, c/tanh/h chain, LDS write->read
// turnaround) has nothing to overlap with at 1 wave/SIMD.
// Fix: pack NB=2 independent recurrences into one wave. U lives once in
// AGPRs (batch-invariant); only h/c/acc/x/rb duplicate (~40 VGPRs).
// The two chains interleave: b1's 104 pk_fma issue during b0's tail and
// vice versa -> software latency hiding, the only kind available here.
__global__ __launch_bounds__(64, 1) void lstm_seq_kernel(
    const float* __restrict__ x,
    const float* __restrict__ W_w,
    const float* __restrict__ W_b,
    const float* __restrict__ U_w,
    const float* __restrict__ U_b,
    const float* __restrict__ lin_w,
    const float* __restrict__ lin_b,
    float* __restrict__ out)
{
    __shared__ __attribute__((aligned(16))) float hb[NB * 64];  // h broadcast

    const int b0   = blockIdx.x * NB;
    const int lane = threadIdx.x;        // 0..63
    const bool active = lane < HIDDEN;   // lanes 51..63 produce exact zeros
    const int m = active ? lane : 0;

    float ww[4], bbias[4];
#pragma unroll
    for (int g = 0; g < 4; ++g) {
        const int row = m + g * HIDDEN;
        ww[g]    = active ? W_w[row] : 0.f;
        bbias[g] = active ? (W_b[row] + U_b[row]) : 0.f;
    }
    const float lw = active ? lin_w[m] : 0.f;
    const float lb = lin_b[0];

    // U packed over k-pairs: Up[g][j] = {U[row][2j], U[row][2j+1]}, j<26.
    // k==51 is a zero pad (matches hb[n*64+51]==0 from lane 51's h==0).
    v2f Up[4][26];
#pragma unroll
    for (int j = 0; j < 26; ++j) {
        const int k0 = 2 * j, k1 = 2 * j + 1;
#pragma unroll
        for (int g = 0; g < 4; ++g) {
            const int row = m + g * HIDDEN;
            v2f u;
            u.x = (active && k0 < HIDDEN) ? U_w[row * HIDDEN + k0] : 0.f;
            u.y = (active && k1 < HIDDEN) ? U_w[row * HIDDEN + k1] : 0.f;
            Up[g][j] = u;
        }
    }

    float h[NB], c[NB];
    const float* __restrict__ xr[NB];
    float* __restrict__ orow[NB];
#pragma unroll
    for (int n = 0; n < NB; ++n) {
        h[n] = 0.f; c[n] = 0.f;
        xr[n]   = x   + (long)(b0 + n) * LSEQ;
        orow[n] = out + (long)(b0 + n) * LSEQ;
        hb[n * 64 + lane] = 0.f;          // single wave: in-order LDS pipe
    }
    __builtin_amdgcn_wave_barrier();      // compile-time ordering insurance

    for (int T = 0; T < LSEQ; T += UNROLL) {
        float xg[NB][UNROLL], rb[NB][UNROLL];
#pragma unroll
        for (int n = 0; n < NB; ++n)
#pragma unroll
            for (int s = 0; s < UNROLL; ++s) xg[n][s] = xr[n][T + s];  // uniform

#pragma unroll
        for (int s = 0; s < UNROLL; ++s) {
            v2f a[NB][4];
#pragma unroll
            for (int n = 0; n < NB; ++n)
#pragma unroll
                for (int g = 0; g < 4; ++g) a[n][g] = (v2f){0.f, 0.f};

#pragma unroll
            for (int q = 0; q < 13; ++q) {
#pragma unroll
                for (int n = 0; n < NB; ++n) {
                    // Same-address b128 broadcast: conflict-free, hk in VGPRs.
                    const float4 hv = *(const float4*)&hb[n * 64 + q * 4];
                    const v2f hlo = {hv.x, hv.y};
                    const v2f hhi = {hv.z, hv.w};
                    a[n][0] = __builtin_elementwise_fma(hlo, Up[0][2 * q], a[n][0]);
                    a[n][1] = __builtin_elementwise_fma(hlo, Up[1][2 * q], a[n][1]);
                    a[n][2] = __builtin_elementwise_fma(hlo, Up[2][2 * q], a[n][2]);
                    a[n][3] = __builtin_elementwise_fma(hlo, Up[3][2 * q], a[n][3]);
                    a[n][0] = __builtin_elementwise_fma(hhi, Up[0][2 * q + 1], a[n][0]);
                    a[n][1] = __builtin_elementwise_fma(hhi, Up[1][2 * q + 1], a[n][1]);
                    a[n][2] = __builtin_elementwise_fma(hhi, Up[2][2 * q + 1], a[n][2]);
                    a[n][3] = __builtin_elementwise_fma(hhi, Up[3][2 * q + 1], a[n][3]);
                }
            }

            // Tails interleaved: two independent serial chains overlap.
#pragma unroll
            for (int n = 0; n < NB; ++n) {
                const float gi = a[n][0].x + a[n][0].y + fmaf(xg[n][s], ww[0], bbias[0]);
                const float gf = a[n][1].x + a[n][1].y + fmaf(xg[n][s], ww[1], bbias[1]);
                const float gg = a[n][2].x + a[n][2].y + fmaf(xg[n][s], ww[2], bbias[2]);
                const float go = a[n][3].x + a[n][3].y + fmaf(xg[n][s], ww[3], bbias[3]);

                // NOTE: faithful to reference -- no sigmoid on gates.
                c[n] = fmaf(gf, c[n], gi * gg);
                h[n] = go * fast_tanh(c[n]);   // inactive lanes stay exactly 0
                rb[n][s] = h[n] * lw;
            }

            __builtin_amdgcn_wave_barrier();  // reads above precede writes
#pragma unroll
            for (int n = 0; n < NB; ++n) hb[n * 64 + lane] = h[n];
            __builtin_amdgcn_wave_barrier();  // writes precede next reads
        }

        // 2*8 independent butterflies -- swizzle latencies overlap.
#pragma unroll
        for (int n = 0; n < NB; ++n)
#pragma unroll
            for (int s = 0; s < UNROLL; ++s)
#pragma unroll
                for (int off = 32; off > 0; off >>= 1)
                    rb[n][s] += __shfl_xor(rb[n][s], off, 64);

        if (lane == 0) {
#pragma unroll
            for (int n = 0; n < NB; ++n) {
                float4 o0 = {rb[n][0] + lb, rb[n][1] + lb, rb[n][2] + lb, rb[n][3] + lb};
                float4 o1 = {rb[n][4] + lb, rb[n][5] + lb, rb[n][6] + lb, rb[n][7] + lb};
                *(float4*)&orow[n][T]     = o0;  // rows 16B-aligned (4000B stride)
                *(float4*)&orow[n][T + 4] = o1;
            }
        }
    }
}

extern "C" void kernel_launch(void* const* d_in, const int* in_sizes, int n_in,
                              void* d_out, int out_size, void* d_ws, size_t ws_size,
                              hipStream_t stream) {
    const float* x     = (const float*)d_in[0];
    const float* W_w   = (const float*)d_in[1];
    const float* W_b   = (const float*)d_in[2];
    const float* U_w   = (const float*)d_in[3];
    const float* U_b   = (const float*)d_in[4];
    const float* lin_w = (const float*)d_in[5];
    const float* lin_b = (const float*)d_in[6];
    // d_in[7] = future (static 0; out_size == B*LSEQ)
    float* out = (float*)d_out;

    const int B = in_sizes[0] / LSEQ;  // 1024 (even)
    lstm_seq_kernel<<<dim3(B / NB), dim3(64), 0, stream>>>(
        x, W_w, W_b, U_w, U_b, lin_w, lin_b, out);
}

// Round 2
// 570.674 us; speedup vs baseline: 2.6327x; 2.6327x over previous
//
#include <hip/hip_runtime.h>

#define HIDDEN 51
#define LSEQ 1000
#define UNROLL 8    // steps buffered between butterfly/store groups

typedef float v2f __attribute__((ext_vector_type(2)));

// Branch-free tanh: tanh(v) = 1 - 2/(exp2(2*log2e*v)+1). Saturates to +/-1.
__device__ __forceinline__ float fast_tanh(float v) {
    float e = __builtin_amdgcn_exp2f(v * 2.885390081777927f);  // 2*log2(e)
    float r = __builtin_amdgcn_rcpf(e + 1.0f);
    return fmaf(-2.0f, r, 1.0f);
}

// R2: two specialized waves per batch element (128 threads/block).
// Evidence: R0 = 1 wave/SIMD, VALUBusy 44% -> latency-bound with zero HW
// hiding. R1 (NB=2 in one wave) regressed 2.8x: VGPR 252, occupancy halved,
// half the SIMDs idle. Fix: split the CELL across 2 waves instead --
//   c = gf*c + (gi*gg); h = go*tanh(c)
//   wave0: gate rows {i,g} -> p = gi*gg  (1 float/lane to LDS)
//   wave1: gate rows {f,o} -> c, h, h-broadcast, projection butterfly
// Per-wave Up halves (52 floats), VGPR pressure gone, and 2048 waves on
// 1024 SIMDs = 2 waves/SIMD so another block's wave fills the serial-tail
// stalls (LDS turnaround, tanh chain). FMA split into 4 depth-13 chains
// so chain latency (52cy) <= issue (104cy).
__global__ __launch_bounds__(128, 1) void lstm_seq_kernel(
    const float* __restrict__ x,
    const float* __restrict__ W_w,
    const float* __restrict__ W_b,
    const float* __restrict__ U_w,
    const float* __restrict__ U_b,
    const float* __restrict__ lin_w,
    const float* __restrict__ lin_b,
    float* __restrict__ out)
{
    __shared__ __attribute__((aligned(16))) float hb[64];  // h broadcast
    __shared__ __attribute__((aligned(16))) float pb[64];  // p = gi*gg

    const int b    = blockIdx.x;
    const int tid  = threadIdx.x;
    const int wave = tid >> 6;           // 0 or 1 (wave-uniform)
    const int lane = tid & 63;           // 0..63
    const bool active = lane < HIDDEN;   // lanes 51..63 produce exact zeros
    const int m = active ? lane : 0;

    // Gate rows for this wave: wave0 -> {i(0), g(2)}, wave1 -> {f(1), o(3)}.
    const int ga = wave;                 // 0 or 1
    const int gbq = wave + 2;            // 2 or 3
    const int row0 = m + ga  * HIDDEN;
    const int row1 = m + gbq * HIDDEN;

    const float ww0 = active ? W_w[row0] : 0.f;
    const float ww1 = active ? W_w[row1] : 0.f;
    const float bb0 = active ? (W_b[row0] + U_b[row0]) : 0.f;
    const float bb1 = active ? (W_b[row1] + U_b[row1]) : 0.f;
    const float lw  = active ? lin_w[m] : 0.f;
    const float lb  = lin_b[0];

    // U packed over k-pairs: Upg[j] = {U[row][2j], U[row][2j+1]}, j<26.
    // k==51 is a zero pad (matches hb[51]==0 from lane 51's h==0).
    v2f Up0[26], Up1[26];
#pragma unroll
    for (int j = 0; j < 26; ++j) {
        const int k0 = 2 * j, k1 = 2 * j + 1;
        v2f u0, u1;
        u0.x = (active && k0 < HIDDEN) ? U_w[row0 * HIDDEN + k0] : 0.f;
        u0.y = (active && k1 < HIDDEN) ? U_w[row0 * HIDDEN + k1] : 0.f;
        u1.x = (active && k0 < HIDDEN) ? U_w[row1 * HIDDEN + k0] : 0.f;
        u1.y = (active && k1 < HIDDEN) ? U_w[row1 * HIDDEN + k1] : 0.f;
        Up0[j] = u0;
        Up1[j] = u1;
    }

    float c = 0.f;                        // live in wave1 only
    const float* __restrict__ xrow = x + (long)b * LSEQ;
    float* __restrict__ orow = out + (long)b * LSEQ;

    if (wave == 1) hb[lane] = 0.f;
    __syncthreads();

    for (int T = 0; T < LSEQ; T += UNROLL) {
        float xg[UNROLL], rb[UNROLL];
#pragma unroll
        for (int s = 0; s < UNROLL; ++s) xg[s] = xrow[T + s];  // uniform

#pragma unroll
        for (int s = 0; s < UNROLL; ++s) {
            // 4 independent depth-13 chains: latency 52cy <= issue 104cy.
            v2f aL0 = {0.f, 0.f}, aH0 = {0.f, 0.f};
            v2f aL1 = {0.f, 0.f}, aH1 = {0.f, 0.f};
#pragma unroll
            for (int q = 0; q < 13; ++q) {
                // Same-address b128 broadcast: conflict-free, hk in VGPRs.
                const float4 hv = *(const float4*)&hb[q * 4];
                const v2f hlo = {hv.x, hv.y};
                const v2f hhi = {hv.z, hv.w};
                aL0 = __builtin_elementwise_fma(hlo, Up0[2 * q],     aL0);
                aL1 = __builtin_elementwise_fma(hlo, Up1[2 * q],     aL1);
                aH0 = __builtin_elementwise_fma(hhi, Up0[2 * q + 1], aH0);
                aH1 = __builtin_elementwise_fma(hhi, Up1[2 * q + 1], aH1);
            }
            const float d0 = (aL0.x + aL0.y) + (aH0.x + aH0.y)
                           + fmaf(xg[s], ww0, bb0);   // gi (w0) / gf (w1)
            const float d1 = (aL1.x + aL1.y) + (aH1.x + aH1.y)
                           + fmaf(xg[s], ww1, bb1);   // gg (w0) / go (w1)

            if (wave == 0) {
                pb[lane] = d0 * d1;                   // p = gi*gg
            }
            __syncthreads();   // A: p visible; w0's hb reads done before
                               //    w1 overwrites hb below
            if (wave == 1) {
                // NOTE: faithful to reference -- no sigmoid on gates.
                c = fmaf(d0, c, pb[lane]);            // c = gf*c + gi*gg
                const float h = d1 * fast_tanh(c);    // h = go*tanh(c)
                hb[lane] = h;                         // inactive lanes: 0
                rb[s] = h * lw;
            }
            __syncthreads();   // B: new h visible to both waves
        }

        if (wave == 1) {
            // 8 independent butterflies -- swizzle latencies overlap.
#pragma unroll
            for (int s = 0; s < UNROLL; ++s)
#pragma unroll
                for (int off = 32; off > 0; off >>= 1)
                    rb[s] += __shfl_xor(rb[s], off, 64);
            if (lane == 0) {
                float4 o0 = {rb[0] + lb, rb[1] + lb, rb[2] + lb, rb[3] + lb};
                float4 o1 = {rb[4] + lb, rb[5] + lb, rb[6] + lb, rb[7] + lb};
                *(float4*)&orow[T]     = o0;  // 16B-aligned (4000B stride)
                *(float4*)&orow[T + 4] = o1;
            }
        }
    }
}

extern "C" void kernel_launch(void* const* d_in, const int* in_sizes, int n_in,
                              void* d_out, int out_size, void* d_ws, size_t ws_size,
                              hipStream_t stream) {
    const float* x     = (const float*)d_in[0];
    const float* W_w   = (const float*)d_in[1];
    const float* W_b   = (const float*)d_in[2];
    const float* U_w   = (const float*)d_in[3];
    const float* U_b   = (const float*)d_in[4];
    const float* lin_w = (const float*)d_in[5];
    const float* lin_b = (const float*)d_in[6];
    // d_in[7] = future (static 0; out_size == B*LSEQ)
    float* out = (float*)d_out;

    const int B = in_sizes[0] / LSEQ;  // 1024
    lstm_seq_kernel<<<dim3(B), dim3(128), 0, stream>>>(
        x, W_w, W_b, U_w, U_b, lin_w, lin_b, out);
}